// Round 1
// baseline (1005.375 us; speedup 1.0000x reference)
//
#include <hip/hip_runtime.h>
#include <math.h>

#define N_NODES 10000
#define K1 10
#define K2 25
#define DIM 64
#define OUT 128
#define NGRAPH 64

#define NPB 2               // nodes per block
#define RPB (NPB * K1)      // 20 a12 rows per block
#define XROWS (RPB + NPB)   // + 2 a01 rows = 22
#define QP 36               // k-quarter pitch: 32 data + 4 pad floats
#define XPITCH (4 * QP)     // 144 floats per x row
#define QP1 68              // round-1 quarter pitch: 64 data + 4 pad
#define X1PITCH (4 * QP1)   // 272 floats per x1 row

// ---------------------------------------------------------------------------
// Fused kernel: per block = 2 nodes.
//  phase 1 (no barriers): wave w owns x-rows {w, w+4, ..., w+16}; lane l =
//    column l sums 25 h2 rows (25 independent 256B-coalesced loads) -> LDS.
//  phase 2: lane = (k-quarter kq=l&3, col-pair cp=l>>2). 22 matvecs through
//    w0 held in regs; partials combined intra-quad via shfl_xor butterfly.
//    Rows 0..19 -> a12mean accumulators (regs); rows 20,21 -> a01 -> x1.
//  round 1: same decomposition over k=256 with w1 (2 sub-chunks of 32 to cap
//    registers); run-length seg atomicAdd from kq==0 lanes.
//  LDS quarters padded (pitch 36/68) so the 4 quarter-streams hit disjoint
//  banks: conflict-free broadcast ds_read_b128.
// ---------------------------------------------------------------------------
__global__ __launch_bounds__(256, 4) void kFused(
    const float* __restrict__ h0, const float* __restrict__ h1,
    const float* __restrict__ h2, const float* __restrict__ w0,
    const float* __restrict__ b0, const float* __restrict__ w1,
    const float* __restrict__ b1, const int* __restrict__ gids,
    float* __restrict__ seg)
{
    __shared__ float xbuf[XROWS][XPITCH];   // 22*144*4 = 12672 B
    __shared__ float x1p[NPB][X1PITCH];     //  2*272*4 =  2176 B

    const int t  = threadIdx.x;
    const int w  = t >> 6;          // wave 0..3
    const int l  = t & 63;          // lane
    const int kq = l & 3;           // k-quarter owner within quad
    const int cp = l >> 2;          // col-pair within wave
    const int c0 = w * 32 + cp * 2; // first of this lane's 2 output cols
    const int n0 = blockIdx.x * NPB;

    // w0 register slice: rows kq*32+kk, cols c0/c0+1 (L2-resident)
    float w0r0[32], w0r1[32];
#pragma unroll
    for (int kk = 0; kk < 32; ++kk) {
        w0r0[kk] = w0[(kq * 32 + kk) * OUT + c0];
        w0r1[kk] = w0[(kq * 32 + kk) * OUT + c0 + 1];
    }
    const float b00 = b0[c0], b01 = b0[c0 + 1];

    // h0 rows -> xbuf rows 20,21, quarters 0,1 (first half of a01's x)
    if (t < NPB * DIM) {
        const int i = t >> 6, cl = t & 63;
        xbuf[RPB + i][(cl >> 5) * QP + (cl & 31)] = h0[(size_t)(n0 + i) * DIM + cl];
    }

    // ---- phase 1: h2 means + h1 rows, wave-per-row, barrier-free ----
#pragma unroll 1
    for (int q = 0; q < 5; ++q) {
        const int rloc = w + 4 * q;                 // 0..19
        const size_t rg = (size_t)n0 * K1 + rloc;   // global h1-row index
        const float* hb = h2 + rg * (size_t)(K2 * DIM) + l;
        float s = 0.f;
#pragma unroll
        for (int row = 0; row < K2; ++row)
            s += __builtin_nontemporal_load(hb + row * DIM);
        xbuf[rloc][(2 + (l >> 5)) * QP + (l & 31)] = s * (1.f / K2); // mean -> q2,q3
        xbuf[rloc][(l >> 5) * QP + (l & 31)]       = h1[rg * DIM + l]; // h1 -> q0,q1
    }
    __syncthreads();

    // h1-mean -> xbuf rows 20,21 quarters 2,3 (second half of a01's x)
    if (t < NPB * DIM) {
        const int i = t >> 6, cl = t & 63;
        float s = 0.f;
#pragma unroll
        for (int j = 0; j < K1; ++j)
            s += xbuf[i * K1 + j][(cl >> 5) * QP + (cl & 31)];
        xbuf[RPB + i][(2 + (cl >> 5)) * QP + (cl & 31)] = s * (1.f / K1);
    }
    __syncthreads();

    // ---- phase 2: 22 matvecs through w0, quad-butterfly combine ----
    float accA0 = 0.f, accA1 = 0.f, accB0 = 0.f, accB1 = 0.f;
#pragma unroll 2
    for (int j = 0; j < XROWS; ++j) {
        const float4* xq = (const float4*)&xbuf[j][kq * QP];
        float p0 = 0.f, p1 = 0.f;
#pragma unroll
        for (int m = 0; m < 8; ++m) {
            const float4 x4 = xq[m];
            p0 += x4.x * w0r0[4*m]   + x4.y * w0r0[4*m+1]
                + x4.z * w0r0[4*m+2] + x4.w * w0r0[4*m+3];
            p1 += x4.x * w0r1[4*m]   + x4.y * w0r1[4*m+1]
                + x4.z * w0r1[4*m+2] + x4.w * w0r1[4*m+3];
        }
        p0 += __shfl_xor(p0, 1);  p0 += __shfl_xor(p0, 2);
        p1 += __shfl_xor(p1, 1);  p1 += __shfl_xor(p1, 2);
        const float y0 = fmaxf(p0 + b00, 0.f);
        const float y1 = fmaxf(p1 + b01, 0.f);
        if (j < K1)        { accA0 += y0; accA1 += y1; }       // node 0 a12 sum
        else if (j < RPB)  { accB0 += y0; accB1 += y1; }       // node 1 a12 sum
        else if (kq == 0) {                                     // a01 -> x1[0:128)
            const int i = j - RPB;
            float2* dst = (float2*)&x1p[i][(c0 >> 6) * QP1 + (c0 & 63)];
            *dst = make_float2(y0, y1);
        }
    }
    if (kq == 0) {                                              // a12mean -> x1[128:256)
        const int C = OUT + c0;
        float2* d0 = (float2*)&x1p[0][(C >> 6) * QP1 + (C & 63)];
        *d0 = make_float2(accA0 * (1.f / K1), accA1 * (1.f / K1));
        float2* d1 = (float2*)&x1p[1][(C >> 6) * QP1 + (C & 63)];
        *d1 = make_float2(accB0 * (1.f / K1), accB1 * (1.f / K1));
    }
    __syncthreads();

    // ---- round 1: k=256 through w1, 2 sub-chunks of 32 k's (reg cap) ----
    float pr00 = 0.f, pr01 = 0.f, pr10 = 0.f, pr11 = 0.f;
#pragma unroll 1
    for (int hh = 0; hh < 2; ++hh) {
        float w1r0[32], w1r1[32];
#pragma unroll
        for (int kk = 0; kk < 32; ++kk) {
            const int krow = kq * 64 + hh * 32 + kk;
            w1r0[kk] = w1[krow * OUT + c0];
            w1r1[kk] = w1[krow * OUT + c0 + 1];
        }
        {
            const float4* xq = (const float4*)&x1p[0][kq * QP1 + hh * 32];
            float p0 = 0.f, p1 = 0.f;
#pragma unroll
            for (int m = 0; m < 8; ++m) {
                const float4 x4 = xq[m];
                p0 += x4.x*w1r0[4*m] + x4.y*w1r0[4*m+1] + x4.z*w1r0[4*m+2] + x4.w*w1r0[4*m+3];
                p1 += x4.x*w1r1[4*m] + x4.y*w1r1[4*m+1] + x4.z*w1r1[4*m+2] + x4.w*w1r1[4*m+3];
            }
            pr00 += p0; pr01 += p1;
        }
        {
            const float4* xq = (const float4*)&x1p[1][kq * QP1 + hh * 32];
            float p0 = 0.f, p1 = 0.f;
#pragma unroll
            for (int m = 0; m < 8; ++m) {
                const float4 x4 = xq[m];
                p0 += x4.x*w1r0[4*m] + x4.y*w1r0[4*m+1] + x4.z*w1r0[4*m+2] + x4.w*w1r0[4*m+3];
                p1 += x4.x*w1r1[4*m] + x4.y*w1r1[4*m+1] + x4.z*w1r1[4*m+2] + x4.w*w1r1[4*m+3];
            }
            pr10 += p0; pr11 += p1;
        }
    }
    const float b10 = b1[c0], b11 = b1[c0 + 1];
    pr00 += __shfl_xor(pr00, 1); pr00 += __shfl_xor(pr00, 2);
    pr01 += __shfl_xor(pr01, 1); pr01 += __shfl_xor(pr01, 2);
    pr10 += __shfl_xor(pr10, 1); pr10 += __shfl_xor(pr10, 2);
    pr11 += __shfl_xor(pr11, 1); pr11 += __shfl_xor(pr11, 2);
    const float o00 = fmaxf(pr00 + b10, 0.f);
    const float o01 = fmaxf(pr01 + b11, 0.f);
    const float o10 = fmaxf(pr10 + b10, 0.f);
    const float o11 = fmaxf(pr11 + b11, 0.f);

    if (kq == 0) {
        const int g0 = gids[n0], g1 = gids[n0 + 1];
        if (g0 == g1) {
            atomicAdd(&seg[g0 * OUT + c0],     o00 + o10);
            atomicAdd(&seg[g0 * OUT + c0 + 1], o01 + o11);
        } else {
            atomicAdd(&seg[g0 * OUT + c0],     o00);
            atomicAdd(&seg[g0 * OUT + c0 + 1], o01);
            atomicAdd(&seg[g1 * OUT + c0],     o10);
            atomicAdd(&seg[g1 * OUT + c0 + 1], o11);
        }
    }
}

// ---------------------------------------------------------------------------
// Kernel C: readout MLP on seg (64 x 128) -> out (64 x 1). One block/graph.
// ---------------------------------------------------------------------------
__global__ void kC(const float* __restrict__ seg,
                   const float* __restrict__ wr1, const float* __restrict__ br1,
                   const float* __restrict__ wr2, const float* __restrict__ br2,
                   const float* __restrict__ wr3, const float* __restrict__ br3,
                   float* __restrict__ out)
{
    __shared__ float r1[35], r2[35];
    const int g = blockIdx.x, l = threadIdx.x;
    const float* s = seg + (size_t)g * OUT;
    const float SCALE = 1.0507009873554805f;
    const float ALPHA = 1.6732632423543772f;

    if (l < 35) {
        float d = br1[l];
        for (int k = 0; k < OUT; ++k) d += s[k] * wr1[k * 35 + l];
        r1[l] = d > 0.f ? SCALE * d : SCALE * ALPHA * (expf(d) - 1.f);
    }
    __syncthreads();
    if (l < 35) {
        float d = br2[l];
        for (int k = 0; k < 35; ++k) d += r1[k] * wr2[k * 35 + l];
        r2[l] = d > 0.f ? SCALE * d : SCALE * ALPHA * (expf(d) - 1.f);
    }
    __syncthreads();
    if (l == 0) {
        float d = br3[0];
        for (int k = 0; k < 35; ++k) d += r2[k] * wr3[k];
        out[g] = d;
    }
}

extern "C" void kernel_launch(void* const* d_in, const int* in_sizes, int n_in,
                              void* d_out, int out_size, void* d_ws, size_t ws_size,
                              hipStream_t stream)
{
    const float* h0  = (const float*)d_in[0];
    const float* h1  = (const float*)d_in[1];
    const float* h2  = (const float*)d_in[2];
    const float* w0  = (const float*)d_in[3];
    const float* b0  = (const float*)d_in[4];
    const float* w1  = (const float*)d_in[5];
    const float* b1  = (const float*)d_in[6];
    const float* wr1 = (const float*)d_in[7];
    const float* br1 = (const float*)d_in[8];
    const float* wr2 = (const float*)d_in[9];
    const float* br2 = (const float*)d_in[10];
    const float* wr3 = (const float*)d_in[11];
    const float* br3 = (const float*)d_in[12];
    const int*  gids = (const int*)d_in[13];
    // d_in[14] = num_graphs (compile-time constant 64)

    float* seg = (float*)d_ws;        // 64*128 floats; a12mean no longer materialized
    float* out = (float*)d_out;

    hipMemsetAsync(seg, 0, NGRAPH * OUT * sizeof(float), stream);
    kFused<<<N_NODES / NPB, 256, 0, stream>>>(h0, h1, h2, w0, b0, w1, b1, gids, seg);
    kC<<<NGRAPH, 64, 0, stream>>>(seg, wr1, br1, wr2, br2, wr3, br3, out);
}

// Round 2
// 1000.642 us; speedup vs baseline: 1.0047x; 1.0047x over previous
//
#include <hip/hip_runtime.h>
#include <math.h>

#define N_NODES 10000
#define K1 10
#define K2 25
#define DIM 64
#define OUT 128
#define NGRAPH 64

#define NPB 2               // nodes per block
#define RPB (NPB * K1)      // 20 a12 rows per block
#define XROWS (RPB + NPB)   // + 2 a01 rows = 22
#define QP 36               // k-quarter pitch: 32 data + 4 pad floats
#define XPITCH (4 * QP)     // 144 floats per x row
#define QP1 68              // round-1 quarter pitch: 64 data + 4 pad
#define X1PITCH (4 * QP1)   // 272 floats per x1 row

// ---------------------------------------------------------------------------
// Fused kernel, register-pressure-staged:
//  phase 1 (no weights live): wave w owns x-rows {w,w+4,..}; lane l = col l
//    sums 25 h2 rows via 25 coalesced NT dword loads -> LDS. ~60 VGPRs peak.
//  w0 regs loaded AFTER phase 1 (overlaps barrier wait), as float2.
//  phase 2 (unroll 1): lane = (k-quarter kq, col-pair cp); 22 matvecs;
//    intra-quad shfl_xor butterfly combines partials. ~90 VGPRs peak.
//  round 1: k=256 through w1 in 2 sub-chunks of 32; run-length seg atomics.
//  launch_bounds(256,3): ~168-VGPR cap = spill insurance; 12 waves/CU.
// ---------------------------------------------------------------------------
__global__ __launch_bounds__(256, 3) void kFused(
    const float* __restrict__ h0, const float* __restrict__ h1,
    const float* __restrict__ h2, const float* __restrict__ w0,
    const float* __restrict__ b0, const float* __restrict__ w1,
    const float* __restrict__ b1, const int* __restrict__ gids,
    float* __restrict__ seg)
{
    __shared__ float xbuf[XROWS][XPITCH];   // 22*144*4 = 12672 B
    __shared__ float x1p[NPB][X1PITCH];     //  2*272*4 =  2176 B

    const int t  = threadIdx.x;
    const int w  = t >> 6;          // wave 0..3
    const int l  = t & 63;          // lane
    const int kq = l & 3;           // k-quarter owner within quad
    const int cp = l >> 2;          // col-pair within wave
    const int c0 = w * 32 + cp * 2; // first of this lane's 2 output cols
    const int n0 = blockIdx.x * NPB;

    // h0 rows -> xbuf rows 20,21, quarters 0,1 (first half of a01's x)
    if (t < NPB * DIM) {
        const int i = t >> 6, cl = t & 63;
        xbuf[RPB + i][(cl >> 5) * QP + (cl & 31)] = h0[(size_t)(n0 + i) * DIM + cl];
    }

    // ---- phase 1: h2 means + h1 rows, wave-per-row, barrier-free ----
    // No weight registers live here: peak pressure = ~25 in-flight loads.
#pragma unroll 1
    for (int q = 0; q < 5; ++q) {
        const int rloc = w + 4 * q;                 // 0..19
        const size_t rg = (size_t)n0 * K1 + rloc;   // global h1-row index
        const float* hb = h2 + rg * (size_t)(K2 * DIM) + l;
        float s = 0.f;
#pragma unroll
        for (int row = 0; row < K2; ++row)
            s += __builtin_nontemporal_load(hb + row * DIM);
        xbuf[rloc][(2 + (l >> 5)) * QP + (l & 31)] = s * (1.f / K2); // mean -> q2,q3
        xbuf[rloc][(l >> 5) * QP + (l & 31)] =
            __builtin_nontemporal_load(&h1[rg * DIM + l]);           // h1 -> q0,q1
    }
    __syncthreads();

    // h1-mean -> xbuf rows 20,21 quarters 2,3 (second half of a01's x)
    if (t < NPB * DIM) {
        const int i = t >> 6, cl = t & 63;
        float s = 0.f;
#pragma unroll
        for (int j = 0; j < K1; ++j)
            s += xbuf[i * K1 + j][(cl >> 5) * QP + (cl & 31)];
        xbuf[RPB + i][(2 + (cl >> 5)) * QP + (cl & 31)] = s * (1.f / K1);
    }

    // w0 register slice (float2: rows kq*32+kk, cols c0,c0+1) — loaded here so
    // it is NOT live across phase 1, and overlaps the barrier wait below.
    float w0r0[32], w0r1[32];
#pragma unroll
    for (int kk = 0; kk < 32; ++kk) {
        const float2 v = *(const float2*)&w0[(kq * 32 + kk) * OUT + c0];
        w0r0[kk] = v.x; w0r1[kk] = v.y;
    }
    const float b00 = b0[c0], b01 = b0[c0 + 1];
    __syncthreads();

    // ---- phase 2: 22 matvecs through w0, quad-butterfly combine ----
    float accA0 = 0.f, accA1 = 0.f, accB0 = 0.f, accB1 = 0.f;
#pragma unroll 1
    for (int j = 0; j < XROWS; ++j) {
        const float4* xq = (const float4*)&xbuf[j][kq * QP];
        float p0 = 0.f, p1 = 0.f;
#pragma unroll
        for (int m = 0; m < 8; ++m) {
            const float4 x4 = xq[m];
            p0 += x4.x * w0r0[4*m]   + x4.y * w0r0[4*m+1]
                + x4.z * w0r0[4*m+2] + x4.w * w0r0[4*m+3];
            p1 += x4.x * w0r1[4*m]   + x4.y * w0r1[4*m+1]
                + x4.z * w0r1[4*m+2] + x4.w * w0r1[4*m+3];
        }
        p0 += __shfl_xor(p0, 1);  p0 += __shfl_xor(p0, 2);
        p1 += __shfl_xor(p1, 1);  p1 += __shfl_xor(p1, 2);
        const float y0 = fmaxf(p0 + b00, 0.f);
        const float y1 = fmaxf(p1 + b01, 0.f);
        if (j < K1)        { accA0 += y0; accA1 += y1; }       // node 0 a12 sum
        else if (j < RPB)  { accB0 += y0; accB1 += y1; }       // node 1 a12 sum
        else if (kq == 0) {                                     // a01 -> x1[0:128)
            const int i = j - RPB;
            float2* dst = (float2*)&x1p[i][(c0 >> 6) * QP1 + (c0 & 63)];
            *dst = make_float2(y0, y1);
        }
    }
    if (kq == 0) {                                              // a12mean -> x1[128:256)
        const int C = OUT + c0;
        float2* d0 = (float2*)&x1p[0][(C >> 6) * QP1 + (C & 63)];
        *d0 = make_float2(accA0 * (1.f / K1), accA1 * (1.f / K1));
        float2* d1 = (float2*)&x1p[1][(C >> 6) * QP1 + (C & 63)];
        *d1 = make_float2(accB0 * (1.f / K1), accB1 * (1.f / K1));
    }
    __syncthreads();

    // ---- round 1: k=256 through w1, 2 sub-chunks of 32 k's (reg cap) ----
    float pr00 = 0.f, pr01 = 0.f, pr10 = 0.f, pr11 = 0.f;
#pragma unroll 1
    for (int hh = 0; hh < 2; ++hh) {
        float w1r0[32], w1r1[32];
#pragma unroll
        for (int kk = 0; kk < 32; ++kk) {
            const int krow = kq * 64 + hh * 32 + kk;
            const float2 v = *(const float2*)&w1[krow * OUT + c0];
            w1r0[kk] = v.x; w1r1[kk] = v.y;
        }
        {
            const float4* xq = (const float4*)&x1p[0][kq * QP1 + hh * 32];
            float p0 = 0.f, p1 = 0.f;
#pragma unroll
            for (int m = 0; m < 8; ++m) {
                const float4 x4 = xq[m];
                p0 += x4.x*w1r0[4*m] + x4.y*w1r0[4*m+1] + x4.z*w1r0[4*m+2] + x4.w*w1r0[4*m+3];
                p1 += x4.x*w1r1[4*m] + x4.y*w1r1[4*m+1] + x4.z*w1r1[4*m+2] + x4.w*w1r1[4*m+3];
            }
            pr00 += p0; pr01 += p1;
        }
        {
            const float4* xq = (const float4*)&x1p[1][kq * QP1 + hh * 32];
            float p0 = 0.f, p1 = 0.f;
#pragma unroll
            for (int m = 0; m < 8; ++m) {
                const float4 x4 = xq[m];
                p0 += x4.x*w1r0[4*m] + x4.y*w1r0[4*m+1] + x4.z*w1r0[4*m+2] + x4.w*w1r0[4*m+3];
                p1 += x4.x*w1r1[4*m] + x4.y*w1r1[4*m+1] + x4.z*w1r1[4*m+2] + x4.w*w1r1[4*m+3];
            }
            pr10 += p0; pr11 += p1;
        }
    }
    const float b10 = b1[c0], b11 = b1[c0 + 1];
    pr00 += __shfl_xor(pr00, 1); pr00 += __shfl_xor(pr00, 2);
    pr01 += __shfl_xor(pr01, 1); pr01 += __shfl_xor(pr01, 2);
    pr10 += __shfl_xor(pr10, 1); pr10 += __shfl_xor(pr10, 2);
    pr11 += __shfl_xor(pr11, 1); pr11 += __shfl_xor(pr11, 2);
    const float o00 = fmaxf(pr00 + b10, 0.f);
    const float o01 = fmaxf(pr01 + b11, 0.f);
    const float o10 = fmaxf(pr10 + b10, 0.f);
    const float o11 = fmaxf(pr11 + b11, 0.f);

    if (kq == 0) {
        const int g0 = gids[n0], g1 = gids[n0 + 1];
        if (g0 == g1) {
            atomicAdd(&seg[g0 * OUT + c0],     o00 + o10);
            atomicAdd(&seg[g0 * OUT + c0 + 1], o01 + o11);
        } else {
            atomicAdd(&seg[g0 * OUT + c0],     o00);
            atomicAdd(&seg[g0 * OUT + c0 + 1], o01);
            atomicAdd(&seg[g1 * OUT + c0],     o10);
            atomicAdd(&seg[g1 * OUT + c0 + 1], o11);
        }
    }
}

// ---------------------------------------------------------------------------
// Kernel C: readout MLP on seg (64 x 128) -> out (64 x 1). One block/graph.
// ---------------------------------------------------------------------------
__global__ void kC(const float* __restrict__ seg,
                   const float* __restrict__ wr1, const float* __restrict__ br1,
                   const float* __restrict__ wr2, const float* __restrict__ br2,
                   const float* __restrict__ wr3, const float* __restrict__ br3,
                   float* __restrict__ out)
{
    __shared__ float r1[35], r2[35];
    const int g = blockIdx.x, l = threadIdx.x;
    const float* s = seg + (size_t)g * OUT;
    const float SCALE = 1.0507009873554805f;
    const float ALPHA = 1.6732632423543772f;

    if (l < 35) {
        float d = br1[l];
        for (int k = 0; k < OUT; ++k) d += s[k] * wr1[k * 35 + l];
        r1[l] = d > 0.f ? SCALE * d : SCALE * ALPHA * (expf(d) - 1.f);
    }
    __syncthreads();
    if (l < 35) {
        float d = br2[l];
        for (int k = 0; k < 35; ++k) d += r1[k] * wr2[k * 35 + l];
        r2[l] = d > 0.f ? SCALE * d : SCALE * ALPHA * (expf(d) - 1.f);
    }
    __syncthreads();
    if (l == 0) {
        float d = br3[0];
        for (int k = 0; k < 35; ++k) d += r2[k] * wr3[k];
        out[g] = d;
    }
}

extern "C" void kernel_launch(void* const* d_in, const int* in_sizes, int n_in,
                              void* d_out, int out_size, void* d_ws, size_t ws_size,
                              hipStream_t stream)
{
    const float* h0  = (const float*)d_in[0];
    const float* h1  = (const float*)d_in[1];
    const float* h2  = (const float*)d_in[2];
    const float* w0  = (const float*)d_in[3];
    const float* b0  = (const float*)d_in[4];
    const float* w1  = (const float*)d_in[5];
    const float* b1  = (const float*)d_in[6];
    const float* wr1 = (const float*)d_in[7];
    const float* br1 = (const float*)d_in[8];
    const float* wr2 = (const float*)d_in[9];
    const float* br2 = (const float*)d_in[10];
    const float* wr3 = (const float*)d_in[11];
    const float* br3 = (const float*)d_in[12];
    const int*  gids = (const int*)d_in[13];
    // d_in[14] = num_graphs (compile-time constant 64)

    float* seg = (float*)d_ws;        // 64*128 floats
    float* out = (float*)d_out;

    hipMemsetAsync(seg, 0, NGRAPH * OUT * sizeof(float), stream);
    kFused<<<N_NODES / NPB, 256, 0, stream>>>(h0, h1, h2, w0, b0, w1, b1, gids, seg);
    kC<<<NGRAPH, 64, 0, stream>>>(seg, wr1, br1, wr2, br2, wr3, br3, out);
}

// Round 3
// 908.341 us; speedup vs baseline: 1.1068x; 1.1016x over previous
//
#include <hip/hip_runtime.h>
#include <math.h>

#define N_NODES 10000
#define K1 10
#define K2 25
#define DIM 64
#define OUT 128
#define NGRAPH 64

#define NPB 2               // nodes per block
#define RPB (NPB * K1)      // 20 a12 rows per block
#define XROWS (RPB + NPB)   // + 2 a01 rows = 22

// ---------------------------------------------------------------------------
// Fused kernel, built from the PROVEN kA/kB patterns (round-0, ~105 us kA):
//  - h1/h0 bulk-loaded as float4 (1 KB/wave-instr, coalesced).
//  - phase 1: wave w owns x-rows {w, w+4, ...}. Lane = (f4col fc=l&15,
//    row-group rg4=l>>4): the wave's 64 lanes read 1 KB CONTIGUOUS of h2 per
//    instr (rows 4k..4k+3 x 16 float4) — same pattern as the 6.3 TB/s float4
//    copy. 6 full loads + 1 guarded (row 24). Partials folded with
//    shfl_xor(16), shfl_xor(32); lanes 0..15 store the mean. No barriers.
//  - phase 2: kA's matvec verbatim: thread owns col c=t&127, k-half h=t>>7;
//    w0 slice in 64 regs; broadcast ds_read_b128 of x; one pbuf combine.
//  - round 1: kB's matvec with w1 in two 64-reg chunks (VGPR < 128 so the
//    whole kernel keeps 4 blocks/CU like kA).
//  - run-length seg atomicAdd (2 nodes).
// ---------------------------------------------------------------------------
__global__ __launch_bounds__(256, 4) void kFused(
    const float* __restrict__ h0, const float* __restrict__ h1,
    const float* __restrict__ h2, const float* __restrict__ w0,
    const float* __restrict__ b0, const float* __restrict__ w1,
    const float* __restrict__ b1, const int* __restrict__ gids,
    float* __restrict__ seg)
{
    __shared__ float xbuf[XROWS][2 * DIM];  // 22*128*4 = 11264 B
    __shared__ float pbuf[XROWS][OUT];      // 22*128*4 = 11264 B
    __shared__ float x1[NPB][2 * OUT];      //  2*256*4 =  2048 B

    const int t  = threadIdx.x;
    const int w  = t >> 6;        // wave 0..3
    const int l  = t & 63;        // lane
    const int c  = t & 127;       // output column (phase 2 / round 1)
    const int h  = t >> 7;        // k-half
    const int n0 = blockIdx.x * NPB;

    // ---- bulk loads: h1 (20 rows) -> xbuf[0:20][0:64], h0 -> xbuf[20:22][0:64]
    {
        const float4* src = (const float4*)(h1 + (size_t)n0 * (K1 * DIM)); // 320 f4
        float4 v = src[t];
        *(float4*)&xbuf[t >> 4][4 * (t & 15)] = v;
        if (t < 64) {
            float4 v2 = src[256 + t];
            *(float4*)&xbuf[16 + (t >> 4)][4 * (t & 15)] = v2;
        }
        if (t < 32) {
            const float4* s0 = (const float4*)(h0 + (size_t)n0 * DIM);     // 32 f4
            *(float4*)&xbuf[RPB + (t >> 4)][4 * (t & 15)] = s0[t];
        }
    }

    // ---- phase 1: h2 means, wave-per-row, 1KB-contiguous float4 loads ----
    {
        const int fc  = l & 15;   // float4 column 0..15
        const int rg4 = l >> 4;   // row-group 0..3
#pragma unroll 1
        for (int q = 0; q < 5; ++q) {
            const int rloc = w + 4 * q;                    // 0..19
            const size_t rg = (size_t)n0 * K1 + rloc;
            const float4* hb = (const float4*)h2 + rg * (K2 * DIM / 4);
            float4 s = make_float4(0.f, 0.f, 0.f, 0.f);
#pragma unroll
            for (int k = 0; k < 6; ++k) {                  // rows 0..23
                const float4 v = hb[(4 * k + rg4) * 16 + fc];
                s.x += v.x; s.y += v.y; s.z += v.z; s.w += v.w;
            }
            if (rg4 == 0) {                                // row 24
                const float4 v = hb[24 * 16 + fc];
                s.x += v.x; s.y += v.y; s.z += v.z; s.w += v.w;
            }
            s.x += __shfl_xor(s.x, 16); s.y += __shfl_xor(s.y, 16);
            s.z += __shfl_xor(s.z, 16); s.w += __shfl_xor(s.w, 16);
            s.x += __shfl_xor(s.x, 32); s.y += __shfl_xor(s.y, 32);
            s.z += __shfl_xor(s.z, 32); s.w += __shfl_xor(s.w, 32);
            if (rg4 == 0) {
                *(float4*)&xbuf[rloc][DIM + 4 * fc] =
                    make_float4(s.x * (1.f / K2), s.y * (1.f / K2),
                                s.z * (1.f / K2), s.w * (1.f / K2));
            }
        }
    }
    __syncthreads();

    // w0 register slice (kA layout): rows h*64+k, col c
    float w0r[64];
#pragma unroll
    for (int k = 0; k < 64; ++k)
        w0r[k] = w0[(h * 64 + k) * OUT + c];
    const float b0r = b0[c];

    // h1-mean -> xbuf rows 20,21 cols 64..127
    if (t < NPB * DIM) {
        const int i = t >> 6, cl = t & 63;
        float s = 0.f;
#pragma unroll
        for (int j = 0; j < K1; ++j)
            s += xbuf[i * K1 + j][cl];
        xbuf[RPB + i][DIM + cl] = s * (1.f / K1);
    }
    __syncthreads();

    // ---- phase 2: 22 matvecs through w0 (kA pattern: broadcast b128) ----
    float myp[XROWS];
#pragma unroll
    for (int j = 0; j < XROWS; ++j) {
        const float4* xj = (const float4*)(&xbuf[j][h * DIM]);
        float p = 0.f;
#pragma unroll
        for (int k4 = 0; k4 < 16; ++k4) {
            const float4 xv = xj[k4];
            p += xv.x * w0r[4 * k4 + 0] + xv.y * w0r[4 * k4 + 1]
               + xv.z * w0r[4 * k4 + 2] + xv.w * w0r[4 * k4 + 3];
        }
        if (h == 1) pbuf[j][c] = p;
        else        myp[j]     = p;
    }
    __syncthreads();
    if (h == 0) {
        float accA = 0.f, accB = 0.f;
#pragma unroll
        for (int j = 0; j < RPB; ++j) {
            float y = myp[j] + pbuf[j][c] + b0r;
            y = fmaxf(y, 0.f);
            if (j < K1) accA += y; else accB += y;
        }
        const float y0 = fmaxf(myp[RPB]     + pbuf[RPB][c]     + b0r, 0.f);
        const float y1 = fmaxf(myp[RPB + 1] + pbuf[RPB + 1][c] + b0r, 0.f);
        x1[0][c] = y0;                       // a01 node 0
        x1[1][c] = y1;                       // a01 node 1
        x1[0][OUT + c] = accA * (1.f / K1);  // a12mean node 0
        x1[1][OUT + c] = accB * (1.f / K1);  // a12mean node 1
    }
    __syncthreads();

    // ---- round 1: k=256 through w1, two 64-reg chunks (VGPR < 128) ----
    float pr0 = 0.f, pr1 = 0.f;
#pragma unroll 1
    for (int half = 0; half < 2; ++half) {
        float w1r[64];
#pragma unroll
        for (int kk = 0; kk < 64; ++kk)
            w1r[kk] = w1[(h * 128 + half * 64 + kk) * OUT + c];
        const float4* xa = (const float4*)(&x1[0][h * OUT + half * 64]);
        const float4* xb = (const float4*)(&x1[1][h * OUT + half * 64]);
        float p0 = 0.f, p1 = 0.f;
#pragma unroll
        for (int k4 = 0; k4 < 16; ++k4) {
            const float4 a = xa[k4];
            p0 += a.x * w1r[4 * k4 + 0] + a.y * w1r[4 * k4 + 1]
                + a.z * w1r[4 * k4 + 2] + a.w * w1r[4 * k4 + 3];
            const float4 b = xb[k4];
            p1 += b.x * w1r[4 * k4 + 0] + b.y * w1r[4 * k4 + 1]
                + b.z * w1r[4 * k4 + 2] + b.w * w1r[4 * k4 + 3];
        }
        pr0 += p0; pr1 += p1;
    }
    if (h == 1) { pbuf[0][c] = pr0; pbuf[1][c] = pr1; }
    __syncthreads();
    if (h == 0) {
        const float b1r = b1[c];
        const float o0 = fmaxf(pr0 + pbuf[0][c] + b1r, 0.f);
        const float o1 = fmaxf(pr1 + pbuf[1][c] + b1r, 0.f);
        const int g0 = gids[n0], g1 = gids[n0 + 1];
        if (g0 == g1) {
            atomicAdd(&seg[g0 * OUT + c], o0 + o1);
        } else {
            atomicAdd(&seg[g0 * OUT + c], o0);
            atomicAdd(&seg[g1 * OUT + c], o1);
        }
    }
}

// ---------------------------------------------------------------------------
// Kernel C: readout MLP on seg (64 x 128) -> out (64 x 1). One block/graph.
// ---------------------------------------------------------------------------
__global__ void kC(const float* __restrict__ seg,
                   const float* __restrict__ wr1, const float* __restrict__ br1,
                   const float* __restrict__ wr2, const float* __restrict__ br2,
                   const float* __restrict__ wr3, const float* __restrict__ br3,
                   float* __restrict__ out)
{
    __shared__ float r1[35], r2[35];
    const int g = blockIdx.x, l = threadIdx.x;
    const float* s = seg + (size_t)g * OUT;
    const float SCALE = 1.0507009873554805f;
    const float ALPHA = 1.6732632423543772f;

    if (l < 35) {
        float d = br1[l];
        for (int k = 0; k < OUT; ++k) d += s[k] * wr1[k * 35 + l];
        r1[l] = d > 0.f ? SCALE * d : SCALE * ALPHA * (expf(d) - 1.f);
    }
    __syncthreads();
    if (l < 35) {
        float d = br2[l];
        for (int k = 0; k < 35; ++k) d += r1[k] * wr2[k * 35 + l];
        r2[l] = d > 0.f ? SCALE * d : SCALE * ALPHA * (expf(d) - 1.f);
    }
    __syncthreads();
    if (l == 0) {
        float d = br3[0];
        for (int k = 0; k < 35; ++k) d += r2[k] * wr3[k];
        out[g] = d;
    }
}

extern "C" void kernel_launch(void* const* d_in, const int* in_sizes, int n_in,
                              void* d_out, int out_size, void* d_ws, size_t ws_size,
                              hipStream_t stream)
{
    const float* h0  = (const float*)d_in[0];
    const float* h1  = (const float*)d_in[1];
    const float* h2  = (const float*)d_in[2];
    const float* w0  = (const float*)d_in[3];
    const float* b0  = (const float*)d_in[4];
    const float* w1  = (const float*)d_in[5];
    const float* b1  = (const float*)d_in[6];
    const float* wr1 = (const float*)d_in[7];
    const float* br1 = (const float*)d_in[8];
    const float* wr2 = (const float*)d_in[9];
    const float* br2 = (const float*)d_in[10];
    const float* wr3 = (const float*)d_in[11];
    const float* br3 = (const float*)d_in[12];
    const int*  gids = (const int*)d_in[13];
    // d_in[14] = num_graphs (compile-time constant 64)

    float* seg = (float*)d_ws;        // 64*128 floats
    float* out = (float*)d_out;

    hipMemsetAsync(seg, 0, NGRAPH * OUT * sizeof(float), stream);
    kFused<<<N_NODES / NPB, 256, 0, stream>>>(h0, h1, h2, w0, b0, w1, b1, gids, seg);
    kC<<<NGRAPH, 64, 0, stream>>>(seg, wr1, br1, wr2, br2, wr3, br3, out);
}